// Round 7
// baseline (213.087 us; speedup 1.0000x reference)
//
#include <hip/hip_runtime.h>
#include <math.h>

#define NELEM 1048576    // B*C*H*W
#define NBLK 2048        // 8 blocks/CU on 256 CUs
#define ITERS 2          // 4 element-quads (256 elems) per iter -> 512 elems/block
#define LOG2E 1.44269504088896340736f
#define LN2   0.69314718055994530942f

typedef float f32x4 __attribute__((ext_vector_type(4)));

// 4 lanes per element; FOUR elements in flight per iteration with all twelve
// 16B nontemporal loads issued before any consumer.
__global__ __launch_bounds__(256) void coupling_kernel(
    const float* __restrict__ x_change, const float* __restrict__ x_id,
    const float* __restrict__ a, const float* __restrict__ b,
    const f32x4* __restrict__ pi4, const f32x4* __restrict__ mu4,
    const f32x4* __restrict__ s4, float* __restrict__ out) {
    const int t = threadIdx.x;
    const int kq = t & 3;          // component-quad owned by this lane
    const int g = t >> 2;          // element group 0..63
    const int e0 = blockIdx.x * 512;

    // identity passthrough, float4-coalesced, overlaps everything
    if (t < 128) {
        ((f32x4*)(out + NELEM + e0))[t] = ((const f32x4*)(x_id + e0))[t];
    }

    float ldj = 0.0f;
    for (int it = 0; it < ITERS; ++it) {
        const int base = e0 + it * 256 + g;
        f32x4 P[4], M[4], S[4];
        float xv[4], av[4], bv[4];
        // ---- 12 independent nontemporal 16B loads, batch-issued ----
#pragma unroll
        for (int q = 0; q < 4; ++q) {
            const size_t fi = (size_t)(base + q * 64) * 4 + kq;
            P[q] = __builtin_nontemporal_load(pi4 + fi);
            M[q] = __builtin_nontemporal_load(mu4 + fi);
            S[q] = __builtin_nontemporal_load(s4 + fi);
        }
#pragma unroll
        for (int q = 0; q < 4; ++q) {
            const int e = base + q * 64;
            xv[q] = x_change[e]; av[q] = a[e]; bv[q] = b[e];
        }

        float ps[4] = {0.f, 0.f, 0.f, 0.f}, cdf[4] = {0.f, 0.f, 0.f, 0.f};
        float omu[4] = {0.f, 0.f, 0.f, 0.f}, pdf[4] = {0.f, 0.f, 0.f, 0.f};
#pragma unroll
        for (int j = 0; j < 4; ++j) {
#pragma unroll
            for (int q = 0; q < 4; ++q) {   // 4 independent chains -> ILP
                const float wk = __builtin_amdgcn_exp2f(P[q][j] * LOG2E);
                const float ez = __builtin_amdgcn_exp2f(-S[q][j] * LOG2E);
                const float z = (xv[q] - M[q][j]) * ez;
                const float enz = __builtin_amdgcn_exp2f(-z * LOG2E);
                const float gg = __builtin_amdgcn_rcpf(1.0f + enz);
                const float wg = wk * gg;
                ps[q] += wk; cdf[q] += wg; omu[q] += wg * enz;
                pdf[q] += wk * ez * gg * gg * enz;
            }
        }
#pragma unroll
        for (int q = 0; q < 4; ++q) {
            ps[q] += __shfl_xor(ps[q], 1);  ps[q] += __shfl_xor(ps[q], 2);
            cdf[q] += __shfl_xor(cdf[q], 1); cdf[q] += __shfl_xor(cdf[q], 2);
            omu[q] += __shfl_xor(omu[q], 1); omu[q] += __shfl_xor(omu[q], 2);
            pdf[q] += __shfl_xor(pdf[q], 1); pdf[q] += __shfl_xor(pdf[q], 2);
        }

        if (kq == 0) {
#pragma unroll
            for (int q = 0; q < 4; ++q) {
                const float l2ps = __builtin_amdgcn_logf(ps[q]);
                const float l2c  = __builtin_amdgcn_logf(cdf[q]);
                const float l2o  = __builtin_amdgcn_logf(fmaxf(omu[q], 1e-38f));
                const float l2p  = __builtin_amdgcn_logf(fmaxf(pdf[q], 1e-38f));
                const int e = base + q * 64;
                out[e] = ((l2c - l2o) * LN2 + bv[q]) * __builtin_amdgcn_exp2f(av[q] * LOG2E);
                ldj += (l2p + l2ps - l2c - l2o) * LN2 + av[q];
            }
        }
    }

    // ---- block reduction; block (512 elems) lies within one batch ----
    float v = ldj;
#pragma unroll
    for (int off = 32; off > 0; off >>= 1) v += __shfl_down(v, off);
    __shared__ float ws[4];
    const int w = t >> 6;
    if ((t & 63) == 0) ws[w] = v;
    __syncthreads();
    if (t == 0) {
        const float tot = ws[0] + ws[1] + ws[2] + ws[3];
        const int batch = blockIdx.x >> 6;   // 64 blocks (512 elems each) per batch
        atomicAdd(out + 2 * (size_t)NELEM + batch, tot);
    }
}

extern "C" void kernel_launch(void* const* d_in, const int* in_sizes, int n_in,
                              void* d_out, int out_size, void* d_ws, size_t ws_size,
                              hipStream_t stream) {
    const float* x_change = (const float*)d_in[0];
    const float* x_id     = (const float*)d_in[1];
    const float* sldj     = (const float*)d_in[2];
    const float* a        = (const float*)d_in[3];
    const float* b        = (const float*)d_in[4];
    const f32x4* pi       = (const f32x4*)d_in[5];
    const f32x4* mu       = (const f32x4*)d_in[6];
    const f32x4* s        = (const f32x4*)d_in[7];
    float* out = (float*)d_out;

    const int B = in_sizes[2];

    // Seed sldj output region (harness poisons d_out) with a tiny d2d copy;
    // the kernel atomically accumulates into it (stream-ordered).
    hipMemcpyAsync(out + 2 * (size_t)NELEM, sldj, B * sizeof(float),
                   hipMemcpyDeviceToDevice, stream);

    coupling_kernel<<<NBLK, 256, 0, stream>>>(x_change, x_id, a, b, pi, mu, s, out);
}